// Round 20
// baseline (2246.063 us; speedup 1.0000x reference)
//
#include <hip/hip_runtime.h>

// ---------------------------------------------------------------------------
// MTSLTM (time-aware LSTM), B=64 T=512 D=256 H=512 — round 20 (= r19 + racing
// speculation + rlog hoist). Persistent kernel: 64 blocks x 512 threads.
// Grid: 4 batch-groups (16 batches, bg=bid&3) x 16 col-slices (32 h-cols).
// Exchange: agent-scope sc1, self-validating tagged words (no flags):
//   word = (h_bf16<<16) | c_bf16 | ((t>>1)&1)<<14  (bit14 free: tanh range;
//   +-1 skew bound from mutual dependency -> 1-bit epoch suffices;
//   per-launch memset(0xFF) kills cross-launch staleness/poison).
// vs r19 (1493us):
//  * RACING spec: hc load issued FIRST in phase 1 (flies under x-stage+xgemm,
//    ~400cy). Valid at check -> zero exposed RTT. Stale -> r19's late load +
//    predicated retry (unchanged fallback). r14 vs r17 bracketed miss/hit;
//    the race gets both sides' best case.
//  * rlog hoist: 1/log(e+td) computed in phase 2 of the PREVIOUS step
//    (hidden under GEMM); cell uses csv*rlog -> ~50-70cy off the
//    producer->consumer critical chain.
// ---------------------------------------------------------------------------

constexpr int kB = 64, kT = 512, kD = 256, kH = 512, kG = 2048;
constexpr int NBLK = 64, NTHR = 512;

typedef __attribute__((ext_vector_type(8))) short short8v;   // 8 bf16
typedef __attribute__((ext_vector_type(4))) float f32x4;
typedef __attribute__((ext_vector_type(4))) unsigned int uint4v;

__device__ __forceinline__ float fsig(float x)  { return 1.0f / (1.0f + __expf(-x)); }
__device__ __forceinline__ float ftanh(float x) { return 2.0f / (1.0f + __expf(-2.0f * x)) - 1.0f; }
__device__ __forceinline__ unsigned short f2bf(float f) {    // RNE f32->bf16
  unsigned u = __float_as_uint(f);
  return (unsigned short)((u + 0x7FFFu + ((u >> 16) & 1u)) >> 16);
}

#define LGKM_BARRIER() asm volatile("s_waitcnt lgkmcnt(0)\n\ts_barrier" ::: "memory")

__global__ __launch_bounds__(NTHR, 1) void mtsltm_kernel(
    const float* __restrict__ inp, const float* __restrict__ tdel,
    const float* __restrict__ Wd,  const float* __restrict__ W,
    const float* __restrict__ U,   const float* __restrict__ bias,
    float* __restrict__ out, unsigned* __restrict__ hc)
{
  // 68.5 KB LDS. h/c/x XOR-swizzled in 16B units (unit' = unit ^ (row&7)).
  __shared__ __align__(16) unsigned short h_lds[16][512];     // 16 KB
  __shared__ __align__(16) unsigned short c_lds[16][512];     // 16 KB
  __shared__ __align__(16) unsigned short x_lds[2][16][256];  // 16 KB (dbuf)
  __shared__ float g5[8][320];   // gate tiles, stride-5 (conflict-free)
  __shared__ float s5[8][320];   // Wd partials, stride-5

  const int tid = threadIdx.x, bid = blockIdx.x;
  const int bg = bid & 3;          // batch group (16-block exchange group)
  const int cs = bid >> 2;         // col slice [0,16): h-cols cs*32..cs*32+32
  const int wv = tid >> 6, ln = tid & 63;
  const int lm = ln & 15, lg = ln >> 4;   // MFMA lane decomposition

  // ---------------- one-time: weights -> VGPRs (bf16 B-fragments) -----------
  const int gcol = (wv >> 1) * kH + cs * 32 + (wv & 1) * 16 + lm;
  short8v bU[16];                                   // U[512][gcol]
  #pragma unroll
  for (int kt = 0; kt < 16; ++kt) {
    short8v v;
    #pragma unroll
    for (int e = 0; e < 8; ++e)
      v[e] = (short)f2bf(U[(size_t)(kt * 32 + lg * 8 + e) * kG + gcol]);
    bU[kt] = v;
  }
  short8v bX[8];                                    // W[256][gcol]
  #pragma unroll
  for (int kt = 0; kt < 8; ++kt) {
    short8v v;
    #pragma unroll
    for (int e = 0; e < 8; ++e)
      v[e] = (short)f2bf(W[(size_t)(kt * 32 + lg * 8 + e) * kG + gcol]);
    bX[kt] = v;
  }
  const int kq = wv >> 1, ns = wv & 1;   // Wd: k-quarter kq, n-tile ns
  short8v bWd[4];
  #pragma unroll
  for (int kt = 0; kt < 4; ++kt) {
    short8v v;
    #pragma unroll
    for (int e = 0; e < 8; ++e)
      v[e] = (short)f2bf(Wd[(size_t)(kq * 128 + kt * 32 + lg * 8 + e) * kH
                            + cs * 32 + ns * 16 + lm]);
    bWd[kt] = v;
  }
  const float bias_r = bias[gcol];

  // ---------------- identities ----------------
  const int r = tid & 15, ch = tid >> 4, rs = r & 7;   // x staging
  const int bgl_r = bg * 16 + r;
  const int row2 = ln >> 2, q = ln & 3;                // hc staging (per wave)
  const int cm = tid >> 5, cj = tid & 31;              // cell: batch cm, col cj
  const int lidx = ((cm >> 2) << 4) | (cj & 15), jr = cm & 3, chf = cj >> 4;
  const size_t bglc = (size_t)bg * 16 + cm;
  const int colg = cs * 32 + cj;
  float c_keep = 0.0f;                                 // exact f32 cell carry
  float o_hold = 0.0f;                                 // deferred out value
  const size_t HID = (size_t)kB * kT * kH;

  auto xgemm = [&](int par) -> f32x4 {   // x[t]-part of gates (+bias)
    f32x4 a = {bias_r, bias_r, bias_r, bias_r};
    #pragma unroll
    for (int kt = 0; kt < 8; ++kt) {
      short8v av = *(const short8v*)&x_lds[par][lm][((kt * 4 + lg) ^ (lm & 7)) * 8];
      a = __builtin_amdgcn_mfma_f32_16x16x32_bf16(av, bX[kt], a, 0, 0, 0);
    }
    return a;
  };

  // ---------------- prologue: stage x[0], prefetch x[1], rlog[0] ------------
  {
    const float* xs = inp + ((size_t)bgl_r * kT + 0) * kD + ch * 8;
    float4 a = *(const float4*)xs, b = *(const float4*)(xs + 4);
    uint4v xv;
    xv.x = (unsigned)f2bf(a.x) | ((unsigned)f2bf(a.y) << 16);
    xv.y = (unsigned)f2bf(a.z) | ((unsigned)f2bf(a.w) << 16);
    xv.z = (unsigned)f2bf(b.x) | ((unsigned)f2bf(b.y) << 16);
    xv.w = (unsigned)f2bf(b.z) | ((unsigned)f2bf(b.w) << 16);
    *(uint4v*)&x_lds[0][r][(ch ^ rs) * 8] = xv;
  }
  float4 xa, xb;
  {
    const float* xs = inp + ((size_t)bgl_r * kT + 1) * kD + ch * 8;
    xa = *(const float4*)xs; xb = *(const float4*)(xs + 4);
  }
  float rlv = 1.0f / __logf(2.71828182845904523536f + tdel[bglc * kT + 0]);
  __syncthreads();

  for (int t = 0; t < kT; ++t) {
    // ============ phase 1: E-spec -> x-stage -> xgemm -> check E / late L ===
    uint4v w0, w1, w2, w3;
    const unsigned* src = nullptr;
    if (t > 0) {   // EARLY racing load: flies under x-stage + xgemm
      src = hc + ((size_t)((t - 1) & 1) * kB + bg * 16 + row2) * kH
               + 64 * wv + 16 * q;
      asm volatile(
        "global_load_dwordx4 %0, %4, off sc1\n\t"
        "global_load_dwordx4 %1, %4, off offset:16 sc1\n\t"
        "global_load_dwordx4 %2, %4, off offset:32 sc1\n\t"
        "global_load_dwordx4 %3, %4, off offset:48 sc1"
        : "=&v"(w0), "=&v"(w1), "=&v"(w2), "=&v"(w3)
        : "v"(src) : "memory");
      __builtin_amdgcn_sched_barrier(0);
    }
    if (t + 1 < kT) {   // stage x[t+1] into the other buffer (regs from ph2(t-1))
      uint4v xv;
      xv.x = (unsigned)f2bf(xa.x) | ((unsigned)f2bf(xa.y) << 16);
      xv.y = (unsigned)f2bf(xa.z) | ((unsigned)f2bf(xa.w) << 16);
      xv.z = (unsigned)f2bf(xb.x) | ((unsigned)f2bf(xb.y) << 16);
      xv.w = (unsigned)f2bf(xb.z) | ((unsigned)f2bf(xb.w) << 16);
      *(uint4v*)&x_lds[(t + 1) & 1][r][(ch ^ rs) * 8] = xv;
    }
    f32x4 xacc = xgemm(t & 1);   // E in flight over the whole xgemm
    if (t > 0) {
      asm volatile("s_waitcnt vmcnt(0)" ::: "memory");
      __builtin_amdgcn_sched_barrier(0);
      const unsigned ep = (((unsigned)(t - 1) >> 1) & 1u) << 14;
      unsigned bad = (w0.x ^ ep) | (w0.y ^ ep) | (w0.z ^ ep) | (w0.w ^ ep)
                   | (w1.x ^ ep) | (w1.y ^ ep) | (w1.z ^ ep) | (w1.w ^ ep)
                   | (w2.x ^ ep) | (w2.y ^ ep) | (w2.z ^ ep) | (w2.w ^ ep)
                   | (w3.x ^ ep) | (w3.y ^ ep) | (w3.z ^ ep) | (w3.w ^ ep);
      bool ok = ((bad & 0x4000u) == 0u);
      int vt = 0;
      while (!__all(ok)) {   // E missed for some lane -> late reload path
        if (++vt > (1 << 16)) break;   // safety valve: fail loud, not hung
        if (vt > 2) asm volatile("s_sleep 1" ::: "memory");
        if (!ok) {   // predicated: only stale lanes reload
          asm volatile(
            "global_load_dwordx4 %0, %4, off sc1\n\t"
            "global_load_dwordx4 %1, %4, off offset:16 sc1\n\t"
            "global_load_dwordx4 %2, %4, off offset:32 sc1\n\t"
            "global_load_dwordx4 %3, %4, off offset:48 sc1\n\t"
            "s_waitcnt vmcnt(0)"
            : "=&v"(w0), "=&v"(w1), "=&v"(w2), "=&v"(w3)
            : "v"(src) : "memory");
          __builtin_amdgcn_sched_barrier(0);
          bad = (w0.x ^ ep) | (w0.y ^ ep) | (w0.z ^ ep) | (w0.w ^ ep)
              | (w1.x ^ ep) | (w1.y ^ ep) | (w1.z ^ ep) | (w1.w ^ ep)
              | (w2.x ^ ep) | (w2.y ^ ep) | (w2.z ^ ep) | (w2.w ^ ep)
              | (w3.x ^ ep) | (w3.y ^ ep) | (w3.z ^ ep) | (w3.w ^ ep);
          ok = ((bad & 0x4000u) == 0u);
        }
      }
      // unpack: word = (h<<16) | c (bit14 = epoch tag, masked off)
      uint4v hA, hB, cA, cB;
      hA.x = (w0.x >> 16) | (w0.y & 0xFFFF0000u);
      hA.y = (w0.z >> 16) | (w0.w & 0xFFFF0000u);
      hA.z = (w1.x >> 16) | (w1.y & 0xFFFF0000u);
      hA.w = (w1.z >> 16) | (w1.w & 0xFFFF0000u);
      hB.x = (w2.x >> 16) | (w2.y & 0xFFFF0000u);
      hB.y = (w2.z >> 16) | (w2.w & 0xFFFF0000u);
      hB.z = (w3.x >> 16) | (w3.y & 0xFFFF0000u);
      hB.w = (w3.z >> 16) | (w3.w & 0xFFFF0000u);
      cA.x = (w0.x & 0xBFFFu) | ((w0.y & 0xBFFFu) << 16);
      cA.y = (w0.z & 0xBFFFu) | ((w0.w & 0xBFFFu) << 16);
      cA.z = (w1.x & 0xBFFFu) | ((w1.y & 0xBFFFu) << 16);
      cA.w = (w1.z & 0xBFFFu) | ((w1.w & 0xBFFFu) << 16);
      cB.x = (w2.x & 0xBFFFu) | ((w2.y & 0xBFFFu) << 16);
      cB.y = (w2.z & 0xBFFFu) | ((w2.w & 0xBFFFu) << 16);
      cB.z = (w3.x & 0xBFFFu) | ((w3.y & 0xBFFFu) << 16);
      cB.w = (w3.z & 0xBFFFu) | ((w3.w & 0xBFFFu) << 16);
      const int rsw = row2 & 7;
      const int ub = 8 * wv + 2 * q;
      *(uint4v*)&h_lds[row2][((ub)     ^ rsw) * 8] = hA;
      *(uint4v*)&h_lds[row2][((ub + 1) ^ rsw) * 8] = hB;
      *(uint4v*)&c_lds[row2][((ub)     ^ rsw) * 8] = cA;
      *(uint4v*)&c_lds[row2][((ub + 1) ^ rsw) * 8] = cB;
    }
    LGKM_BARRIER();                                    // barrier A

    // ============ phase 2: slow VMEM issues + rlog + GEMM ===================
    if (t > 0)   // plain store: L2 ack, never holds a later vmcnt(0) long
      out[(bglc * kT + (t - 1)) * kH + colg] = o_hold;
    if (t + 2 < kT) {   // prefetch x[t+2] (HBM; completes during GEMM+cell)
      const float* xs = inp + ((size_t)bgl_r * kT + (t + 2)) * kD + ch * 8;
      xa = *(const float4*)xs; xb = *(const float4*)(xs + 4);
    }
    float rln = 0.0f;
    if (t + 1 < kT)   // log+rcp hidden under GEMM (off the critical chain)
      rln = 1.0f / __logf(2.71828182845904523536f + tdel[bglc * kT + (t + 1)]);
    if (t > 0) {
      f32x4 a0 = xacc, a1 = {0.f, 0.f, 0.f, 0.f};
      #pragma unroll
      for (int kt = 0; kt < 8; ++kt) {
        short8v av = *(const short8v*)&h_lds[lm][((kt * 4 + lg) ^ (lm & 7)) * 8];
        a0 = __builtin_amdgcn_mfma_f32_16x16x32_bf16(av, bU[kt], a0, 0, 0, 0);
      }
      #pragma unroll
      for (int kt = 8; kt < 16; ++kt) {
        short8v av = *(const short8v*)&h_lds[lm][((kt * 4 + lg) ^ (lm & 7)) * 8];
        a1 = __builtin_amdgcn_mfma_f32_16x16x32_bf16(av, bU[kt], a1, 0, 0, 0);
      }
      f32x4 aw = {0.f, 0.f, 0.f, 0.f};
      #pragma unroll
      for (int kt = 0; kt < 4; ++kt) {
        short8v av = *(const short8v*)&c_lds[lm][((kq * 16 + kt * 4 + lg) ^ (lm & 7)) * 8];
        aw = __builtin_amdgcn_mfma_f32_16x16x32_bf16(av, bWd[kt], aw, 0, 0, 0);
      }
      #pragma unroll
      for (int j = 0; j < 4; ++j) {
        g5[wv][ln * 5 + j] = a0[j] + a1[j];
        s5[wv][ln * 5 + j] = aw[j];
      }
    } else {
      #pragma unroll
      for (int j = 0; j < 4; ++j) g5[wv][ln * 5 + j] = xacc[j];
    }
    LGKM_BARRIER();                                    // barrier B

    // ============ phase 3: cell -> tagged hc store (no flag, no barrier) ====
    {
      float g0 = g5[0 + chf][lidx * 5 + jr];
      float g1 = g5[2 + chf][lidx * 5 + jr];
      float g2 = g5[4 + chf][lidx * 5 + jr];
      float g3 = g5[6 + chf][lidx * 5 + jr];
      float sw = 0.f;
      if (t > 0) {
        #pragma unroll
        for (int q2 = 0; q2 < 4; ++q2) sw += s5[2 * q2 + chf][lidx * 5 + jr];
      }
      float csv  = ftanh(sw);
      float cadj = (c_keep - csv) + csv * rlv;   // rlv precomputed (ph2, t-1)
      float gi = fsig(g0), gf = fsig(g1), gg = ftanh(g2), go = fsig(g3);
      float cnew = fmaf(gf, cadj, gi * gg);
      float tcn  = ftanh(cnew);            // = c_out
      float hout = ftanh(go * tcn);        // = tanh(o * tanh(c_new))
      c_keep = tcn;
      o_hold = hout;
      unsigned wout = ((unsigned)f2bf(hout) << 16) | (unsigned)f2bf(tcn)
                    | (((unsigned)(t >> 1) & 1u) << 14);
      unsigned* dst = hc + ((size_t)(t & 1) * kB + bglc) * kH + colg;
      asm volatile("global_store_dword %0, %1, off sc1"
                   :: "v"(dst), "v"(wout) : "memory");
    }
    rlv = rln;
    // no barrier C: barrier A of the next step orders g5/s5 reuse; x_lds is
    // double-buffered; hc readers self-validate via the epoch tag.
  }

  // ---------------- epilogue: t = kT-1 outputs ------------------------------
  out[(bglc * kT + (kT - 1)) * kH + colg] = o_hold;
  out[HID + bglc * kH + colg] = o_hold;                      // h_t
  out[HID + (size_t)kB * kH + bglc * kH + colg] = c_keep;    // c_t
}

extern "C" void kernel_launch(void* const* d_in, const int* in_sizes, int n_in,
                              void* d_out, int out_size, void* d_ws, size_t ws_size,
                              hipStream_t stream)
{
  const float* inp  = (const float*)d_in[0];
  const float* td   = (const float*)d_in[1];
  const float* Wd   = (const float*)d_in[2];
  const float* W    = (const float*)d_in[3];
  const float* U    = (const float*)d_in[4];
  const float* bias = (const float*)d_in[5];
  float* out = (float*)d_out;

  // ws: hc[2][64][512] u32 (256 KB). Memset 0xFF each launch: tag bit14=1
  // everywhere -> t=1 (epoch 0) rejects any stale/poisoned data.
  unsigned* hc = (unsigned*)d_ws;
  (void)hipMemsetAsync(hc, 0xFF, (size_t)2 * kB * kH * sizeof(unsigned), stream);
  mtsltm_kernel<<<dim3(NBLK), dim3(NTHR), 0, stream>>>(inp, td, Wd, W, U, bias,
                                                       out, hc);
}

// Round 21
// 1804.732 us; speedup vs baseline: 1.2445x; 1.2445x over previous
//
#include <hip/hip_runtime.h>

// ---------------------------------------------------------------------------
// MTSLTM (time-aware LSTM), B=64 T=512 D=256 H=512 — round 21 (= r19 exactly
// + rlog hoist from r20; racing-early-load REVERTED — it recreated r14's
// systematic spec miss with strictly more traffic).
// Persistent kernel: 64 blocks x 512 threads (8 waves), 1 block/CU.
// Grid: 4 batch-groups (16 batches, bg=bid&3) x 16 col-slices (32 h-cols).
// Exchange: agent-scope sc1, self-validating tagged words (no flags):
//   word = (h_bf16<<16) | c_bf16 | ((t>>1)&1)<<14  (bit14 free: tanh range;
//   +-1 skew bound from mutual dependency -> 1-bit epoch suffices;
//   per-launch memset(0xFF) kills cross-launch staleness/poison).
// Structure: mid-xgemm spec issue (r19), predicated per-lane retry (r19),
// 2 lgkm-only barriers/step, slow VMEM confined to phase 2 (r12),
// stride-5 partial layouts (r8), x_lds dbuf (r14).
// NEW vs r19: rlog = 1/log(e+td) computed in phase 2 of the PREVIOUS step
// (hidden under GEMM); phase 3 uses csv*rlog -> ~50-70cy off the serial
// producer->consumer chain.
// ---------------------------------------------------------------------------

constexpr int kB = 64, kT = 512, kD = 256, kH = 512, kG = 2048;
constexpr int NBLK = 64, NTHR = 512;

typedef __attribute__((ext_vector_type(8))) short short8v;   // 8 bf16
typedef __attribute__((ext_vector_type(4))) float f32x4;
typedef __attribute__((ext_vector_type(4))) unsigned int uint4v;

__device__ __forceinline__ float fsig(float x)  { return 1.0f / (1.0f + __expf(-x)); }
__device__ __forceinline__ float ftanh(float x) { return 2.0f / (1.0f + __expf(-2.0f * x)) - 1.0f; }
__device__ __forceinline__ unsigned short f2bf(float f) {    // RNE f32->bf16
  unsigned u = __float_as_uint(f);
  return (unsigned short)((u + 0x7FFFu + ((u >> 16) & 1u)) >> 16);
}

#define LGKM_BARRIER() asm volatile("s_waitcnt lgkmcnt(0)\n\ts_barrier" ::: "memory")

__global__ __launch_bounds__(NTHR, 1) void mtsltm_kernel(
    const float* __restrict__ inp, const float* __restrict__ tdel,
    const float* __restrict__ Wd,  const float* __restrict__ W,
    const float* __restrict__ U,   const float* __restrict__ bias,
    float* __restrict__ out, unsigned* __restrict__ hc)
{
  // 68.5 KB LDS. h/c/x XOR-swizzled in 16B units (unit' = unit ^ (row&7)).
  __shared__ __align__(16) unsigned short h_lds[16][512];     // 16 KB
  __shared__ __align__(16) unsigned short c_lds[16][512];     // 16 KB
  __shared__ __align__(16) unsigned short x_lds[2][16][256];  // 16 KB (dbuf)
  __shared__ float g5[8][320];   // gate tiles, stride-5 (conflict-free)
  __shared__ float s5[8][320];   // Wd partials, stride-5

  const int tid = threadIdx.x, bid = blockIdx.x;
  const int bg = bid & 3;          // batch group (16-block exchange group)
  const int cs = bid >> 2;         // col slice [0,16): h-cols cs*32..cs*32+32
  const int wv = tid >> 6, ln = tid & 63;
  const int lm = ln & 15, lg = ln >> 4;   // MFMA lane decomposition

  // ---------------- one-time: weights -> VGPRs (bf16 B-fragments) -----------
  const int gcol = (wv >> 1) * kH + cs * 32 + (wv & 1) * 16 + lm;
  short8v bU[16];                                   // U[512][gcol]
  #pragma unroll
  for (int kt = 0; kt < 16; ++kt) {
    short8v v;
    #pragma unroll
    for (int e = 0; e < 8; ++e)
      v[e] = (short)f2bf(U[(size_t)(kt * 32 + lg * 8 + e) * kG + gcol]);
    bU[kt] = v;
  }
  short8v bX[8];                                    // W[256][gcol]
  #pragma unroll
  for (int kt = 0; kt < 8; ++kt) {
    short8v v;
    #pragma unroll
    for (int e = 0; e < 8; ++e)
      v[e] = (short)f2bf(W[(size_t)(kt * 32 + lg * 8 + e) * kG + gcol]);
    bX[kt] = v;
  }
  const int kq = wv >> 1, ns = wv & 1;   // Wd: k-quarter kq, n-tile ns
  short8v bWd[4];
  #pragma unroll
  for (int kt = 0; kt < 4; ++kt) {
    short8v v;
    #pragma unroll
    for (int e = 0; e < 8; ++e)
      v[e] = (short)f2bf(Wd[(size_t)(kq * 128 + kt * 32 + lg * 8 + e) * kH
                            + cs * 32 + ns * 16 + lm]);
    bWd[kt] = v;
  }
  const float bias_r = bias[gcol];

  // ---------------- identities ----------------
  const int r = tid & 15, ch = tid >> 4, rs = r & 7;   // x staging
  const int bgl_r = bg * 16 + r;
  const int row2 = ln >> 2, q = ln & 3;                // hc staging (per wave)
  const int cm = tid >> 5, cj = tid & 31;              // cell: batch cm, col cj
  const int lidx = ((cm >> 2) << 4) | (cj & 15), jr = cm & 3, chf = cj >> 4;
  const size_t bglc = (size_t)bg * 16 + cm;
  const int colg = cs * 32 + cj;
  float c_keep = 0.0f;                                 // exact f32 cell carry
  float o_hold = 0.0f;                                 // deferred out value
  const size_t HID = (size_t)kB * kT * kH;

  // ---------------- prologue: stage x[0], prefetch x[1], rlog[0] ------------
  {
    const float* xs = inp + ((size_t)bgl_r * kT + 0) * kD + ch * 8;
    float4 a = *(const float4*)xs, b = *(const float4*)(xs + 4);
    uint4v xv;
    xv.x = (unsigned)f2bf(a.x) | ((unsigned)f2bf(a.y) << 16);
    xv.y = (unsigned)f2bf(a.z) | ((unsigned)f2bf(a.w) << 16);
    xv.z = (unsigned)f2bf(b.x) | ((unsigned)f2bf(b.y) << 16);
    xv.w = (unsigned)f2bf(b.z) | ((unsigned)f2bf(b.w) << 16);
    *(uint4v*)&x_lds[0][r][(ch ^ rs) * 8] = xv;
  }
  float4 xa, xb;
  {
    const float* xs = inp + ((size_t)bgl_r * kT + 1) * kD + ch * 8;
    xa = *(const float4*)xs; xb = *(const float4*)(xs + 4);
  }
  float rlv = 1.0f / __logf(2.71828182845904523536f + tdel[bglc * kT + 0]);
  __syncthreads();

  for (int t = 0; t < kT; ++t) {
    // ============ phase 1: x-stage -> xgemm(4) -> spec -> xgemm(4) -> valid =
    if (t + 1 < kT) {   // stage x[t+1] into the other buffer (regs from ph2(t-1))
      uint4v xv;
      xv.x = (unsigned)f2bf(xa.x) | ((unsigned)f2bf(xa.y) << 16);
      xv.y = (unsigned)f2bf(xa.z) | ((unsigned)f2bf(xa.w) << 16);
      xv.z = (unsigned)f2bf(xb.x) | ((unsigned)f2bf(xb.y) << 16);
      xv.w = (unsigned)f2bf(xb.z) | ((unsigned)f2bf(xb.w) << 16);
      *(uint4v*)&x_lds[(t + 1) & 1][r][(ch ^ rs) * 8] = xv;
    }
    const int xpar = t & 1;
    f32x4 xacc = {bias_r, bias_r, bias_r, bias_r};
    #pragma unroll
    for (int kt = 0; kt < 4; ++kt) {
      short8v av = *(const short8v*)&x_lds[xpar][lm][((kt * 4 + lg) ^ (lm & 7)) * 8];
      xacc = __builtin_amdgcn_mfma_f32_16x16x32_bf16(av, bX[kt], xacc, 0, 0, 0);
    }
    uint4v w0, w1, w2, w3;
    const unsigned* src = nullptr;
    if (t > 0) {   // spec issue mid-xgemm: late enough for visibility,
                   // early enough that the tail MFMAs hide part of the RTT
      __builtin_amdgcn_sched_barrier(0);
      src = hc + ((size_t)((t - 1) & 1) * kB + bg * 16 + row2) * kH
               + 64 * wv + 16 * q;
      asm volatile(
        "global_load_dwordx4 %0, %4, off sc1\n\t"
        "global_load_dwordx4 %1, %4, off offset:16 sc1\n\t"
        "global_load_dwordx4 %2, %4, off offset:32 sc1\n\t"
        "global_load_dwordx4 %3, %4, off offset:48 sc1"
        : "=&v"(w0), "=&v"(w1), "=&v"(w2), "=&v"(w3)
        : "v"(src) : "memory");
      __builtin_amdgcn_sched_barrier(0);
    }
    #pragma unroll
    for (int kt = 4; kt < 8; ++kt) {
      short8v av = *(const short8v*)&x_lds[xpar][lm][((kt * 4 + lg) ^ (lm & 7)) * 8];
      xacc = __builtin_amdgcn_mfma_f32_16x16x32_bf16(av, bX[kt], xacc, 0, 0, 0);
    }
    if (t > 0) {
      asm volatile("s_waitcnt vmcnt(0)" ::: "memory");
      __builtin_amdgcn_sched_barrier(0);
      const unsigned ep = (((unsigned)(t - 1) >> 1) & 1u) << 14;
      unsigned bad = (w0.x ^ ep) | (w0.y ^ ep) | (w0.z ^ ep) | (w0.w ^ ep)
                   | (w1.x ^ ep) | (w1.y ^ ep) | (w1.z ^ ep) | (w1.w ^ ep)
                   | (w2.x ^ ep) | (w2.y ^ ep) | (w2.z ^ ep) | (w2.w ^ ep)
                   | (w3.x ^ ep) | (w3.y ^ ep) | (w3.z ^ ep) | (w3.w ^ ep);
      bool ok = ((bad & 0x4000u) == 0u);
      int vt = 0;
      while (!__all(ok)) {
        if (++vt > (1 << 16)) break;   // safety valve: fail loud, not hung
        if (vt > 2) asm volatile("s_sleep 1" ::: "memory");
        if (!ok) {   // predicated: only stale lanes reload
          asm volatile(
            "global_load_dwordx4 %0, %4, off sc1\n\t"
            "global_load_dwordx4 %1, %4, off offset:16 sc1\n\t"
            "global_load_dwordx4 %2, %4, off offset:32 sc1\n\t"
            "global_load_dwordx4 %3, %4, off offset:48 sc1\n\t"
            "s_waitcnt vmcnt(0)"
            : "=&v"(w0), "=&v"(w1), "=&v"(w2), "=&v"(w3)
            : "v"(src) : "memory");
          __builtin_amdgcn_sched_barrier(0);
          bad = (w0.x ^ ep) | (w0.y ^ ep) | (w0.z ^ ep) | (w0.w ^ ep)
              | (w1.x ^ ep) | (w1.y ^ ep) | (w1.z ^ ep) | (w1.w ^ ep)
              | (w2.x ^ ep) | (w2.y ^ ep) | (w2.z ^ ep) | (w2.w ^ ep)
              | (w3.x ^ ep) | (w3.y ^ ep) | (w3.z ^ ep) | (w3.w ^ ep);
          ok = ((bad & 0x4000u) == 0u);
        }
      }
      // unpack: word = (h<<16) | c (bit14 = epoch tag, masked off)
      uint4v hA, hB, cA, cB;
      hA.x = (w0.x >> 16) | (w0.y & 0xFFFF0000u);
      hA.y = (w0.z >> 16) | (w0.w & 0xFFFF0000u);
      hA.z = (w1.x >> 16) | (w1.y & 0xFFFF0000u);
      hA.w = (w1.z >> 16) | (w1.w & 0xFFFF0000u);
      hB.x = (w2.x >> 16) | (w2.y & 0xFFFF0000u);
      hB.y = (w2.z >> 16) | (w2.w & 0xFFFF0000u);
      hB.z = (w3.x >> 16) | (w3.y & 0xFFFF0000u);
      hB.w = (w3.z >> 16) | (w3.w & 0xFFFF0000u);
      cA.x = (w0.x & 0xBFFFu) | ((w0.y & 0xBFFFu) << 16);
      cA.y = (w0.z & 0xBFFFu) | ((w0.w & 0xBFFFu) << 16);
      cA.z = (w1.x & 0xBFFFu) | ((w1.y & 0xBFFFu) << 16);
      cA.w = (w1.z & 0xBFFFu) | ((w1.w & 0xBFFFu) << 16);
      cB.x = (w2.x & 0xBFFFu) | ((w2.y & 0xBFFFu) << 16);
      cB.y = (w2.z & 0xBFFFu) | ((w2.w & 0xBFFFu) << 16);
      cB.z = (w3.x & 0xBFFFu) | ((w3.y & 0xBFFFu) << 16);
      cB.w = (w3.z & 0xBFFFu) | ((w3.w & 0xBFFFu) << 16);
      const int rsw = row2 & 7;
      const int ub = 8 * wv + 2 * q;
      *(uint4v*)&h_lds[row2][((ub)     ^ rsw) * 8] = hA;
      *(uint4v*)&h_lds[row2][((ub + 1) ^ rsw) * 8] = hB;
      *(uint4v*)&c_lds[row2][((ub)     ^ rsw) * 8] = cA;
      *(uint4v*)&c_lds[row2][((ub + 1) ^ rsw) * 8] = cB;
    }
    LGKM_BARRIER();                                    // barrier A

    // ============ phase 2: slow VMEM issues + rlog + GEMM ===================
    if (t > 0)   // plain store: L2 ack, never holds a later vmcnt(0) long
      out[(bglc * kT + (t - 1)) * kH + colg] = o_hold;
    if (t + 2 < kT) {   // prefetch x[t+2] (HBM; completes during GEMM+cell)
      const float* xs = inp + ((size_t)bgl_r * kT + (t + 2)) * kD + ch * 8;
      xa = *(const float4*)xs; xb = *(const float4*)(xs + 4);
    }
    float rln = 0.0f;
    if (t + 1 < kT)   // log+rcp hidden under GEMM (off the critical chain)
      rln = 1.0f / __logf(2.71828182845904523536f + tdel[bglc * kT + (t + 1)]);
    if (t > 0) {
      f32x4 a0 = xacc, a1 = {0.f, 0.f, 0.f, 0.f};
      #pragma unroll
      for (int kt = 0; kt < 8; ++kt) {
        short8v av = *(const short8v*)&h_lds[lm][((kt * 4 + lg) ^ (lm & 7)) * 8];
        a0 = __builtin_amdgcn_mfma_f32_16x16x32_bf16(av, bU[kt], a0, 0, 0, 0);
      }
      #pragma unroll
      for (int kt = 8; kt < 16; ++kt) {
        short8v av = *(const short8v*)&h_lds[lm][((kt * 4 + lg) ^ (lm & 7)) * 8];
        a1 = __builtin_amdgcn_mfma_f32_16x16x32_bf16(av, bU[kt], a1, 0, 0, 0);
      }
      f32x4 aw = {0.f, 0.f, 0.f, 0.f};
      #pragma unroll
      for (int kt = 0; kt < 4; ++kt) {
        short8v av = *(const short8v*)&c_lds[lm][((kq * 16 + kt * 4 + lg) ^ (lm & 7)) * 8];
        aw = __builtin_amdgcn_mfma_f32_16x16x32_bf16(av, bWd[kt], aw, 0, 0, 0);
      }
      #pragma unroll
      for (int j = 0; j < 4; ++j) {
        g5[wv][ln * 5 + j] = a0[j] + a1[j];
        s5[wv][ln * 5 + j] = aw[j];
      }
    } else {
      #pragma unroll
      for (int j = 0; j < 4; ++j) g5[wv][ln * 5 + j] = xacc[j];
    }
    LGKM_BARRIER();                                    // barrier B

    // ============ phase 3: cell -> tagged hc store (no flag, no barrier) ====
    {
      float g0 = g5[0 + chf][lidx * 5 + jr];
      float g1 = g5[2 + chf][lidx * 5 + jr];
      float g2 = g5[4 + chf][lidx * 5 + jr];
      float g3 = g5[6 + chf][lidx * 5 + jr];
      float sw = 0.f;
      if (t > 0) {
        #pragma unroll
        for (int q2 = 0; q2 < 4; ++q2) sw += s5[2 * q2 + chf][lidx * 5 + jr];
      }
      float csv  = ftanh(sw);
      float cadj = (c_keep - csv) + csv * rlv;   // rlv precomputed (ph2, t-1)
      float gi = fsig(g0), gf = fsig(g1), gg = ftanh(g2), go = fsig(g3);
      float cnew = fmaf(gf, cadj, gi * gg);
      float tcn  = ftanh(cnew);            // = c_out
      float hout = ftanh(go * tcn);        // = tanh(o * tanh(c_new))
      c_keep = tcn;
      o_hold = hout;
      unsigned wout = ((unsigned)f2bf(hout) << 16) | (unsigned)f2bf(tcn)
                    | (((unsigned)(t >> 1) & 1u) << 14);
      unsigned* dst = hc + ((size_t)(t & 1) * kB + bglc) * kH + colg;
      asm volatile("global_store_dword %0, %1, off sc1"
                   :: "v"(dst), "v"(wout) : "memory");
    }
    rlv = rln;
    // no barrier C: barrier A of the next step orders g5/s5 reuse; x_lds is
    // double-buffered; hc readers self-validate via the epoch tag.
  }

  // ---------------- epilogue: t = kT-1 outputs ------------------------------
  out[(bglc * kT + (kT - 1)) * kH + colg] = o_hold;
  out[HID + bglc * kH + colg] = o_hold;                      // h_t
  out[HID + (size_t)kB * kH + bglc * kH + colg] = c_keep;    // c_t
}

extern "C" void kernel_launch(void* const* d_in, const int* in_sizes, int n_in,
                              void* d_out, int out_size, void* d_ws, size_t ws_size,
                              hipStream_t stream)
{
  const float* inp  = (const float*)d_in[0];
  const float* td   = (const float*)d_in[1];
  const float* Wd   = (const float*)d_in[2];
  const float* W    = (const float*)d_in[3];
  const float* U    = (const float*)d_in[4];
  const float* bias = (const float*)d_in[5];
  float* out = (float*)d_out;

  // ws: hc[2][64][512] u32 (256 KB). Memset 0xFF each launch: tag bit14=1
  // everywhere -> t=1 (epoch 0) rejects any stale/poisoned data.
  unsigned* hc = (unsigned*)d_ws;
  (void)hipMemsetAsync(hc, 0xFF, (size_t)2 * kB * kH * sizeof(unsigned), stream);
  mtsltm_kernel<<<dim3(NBLK), dim3(NTHR), 0, stream>>>(inp, td, Wd, W, U, bias,
                                                       out, hc);
}

// Round 22
// 1490.023 us; speedup vs baseline: 1.5074x; 1.2112x over previous
//
#include <hip/hip_runtime.h>

// ---------------------------------------------------------------------------
// MTSLTM (time-aware LSTM), B=64 T=512 D=256 H=512 — round 22 = r19 VERBATIM
// (best: 1493us). r21's rlog hoist reverted: consuming a phase-2 load before
// barrier B forces a FIFO vmcnt wait that re-drains the out[] store + x
// prefetch (the r12 vmcnt-poison) — confirmed by the 1805us regression.
// Persistent kernel: 64 blocks x 512 threads (8 waves), 1 block/CU.
// Grid: 4 batch-groups (16 batches, bg=bid&3) x 16 col-slices (32 h-cols).
// Exchange: agent-scope sc1, self-validating tagged words (no flags):
//   word = (h_bf16<<16) | c_bf16 | ((t>>1)&1)<<14  (bit14 free: tanh range;
//   +-1 skew bound from mutual dependency -> 1-bit epoch suffices;
//   per-launch memset(0xFF) kills cross-launch staleness/poison).
// Structure: mid-xgemm spec issue, predicated per-lane retry, 2 lgkm-only
// barriers/step, slow VMEM confined to phase 2, stride-5 partials, x dbuf.
// ---------------------------------------------------------------------------

constexpr int kB = 64, kT = 512, kD = 256, kH = 512, kG = 2048;
constexpr int NBLK = 64, NTHR = 512;

typedef __attribute__((ext_vector_type(8))) short short8v;   // 8 bf16
typedef __attribute__((ext_vector_type(4))) float f32x4;
typedef __attribute__((ext_vector_type(4))) unsigned int uint4v;

__device__ __forceinline__ float fsig(float x)  { return 1.0f / (1.0f + __expf(-x)); }
__device__ __forceinline__ float ftanh(float x) { return 2.0f / (1.0f + __expf(-2.0f * x)) - 1.0f; }
__device__ __forceinline__ unsigned short f2bf(float f) {    // RNE f32->bf16
  unsigned u = __float_as_uint(f);
  return (unsigned short)((u + 0x7FFFu + ((u >> 16) & 1u)) >> 16);
}

#define LGKM_BARRIER() asm volatile("s_waitcnt lgkmcnt(0)\n\ts_barrier" ::: "memory")

__global__ __launch_bounds__(NTHR, 1) void mtsltm_kernel(
    const float* __restrict__ inp, const float* __restrict__ tdel,
    const float* __restrict__ Wd,  const float* __restrict__ W,
    const float* __restrict__ U,   const float* __restrict__ bias,
    float* __restrict__ out, unsigned* __restrict__ hc)
{
  // 68.5 KB LDS. h/c/x XOR-swizzled in 16B units (unit' = unit ^ (row&7)).
  __shared__ __align__(16) unsigned short h_lds[16][512];     // 16 KB
  __shared__ __align__(16) unsigned short c_lds[16][512];     // 16 KB
  __shared__ __align__(16) unsigned short x_lds[2][16][256];  // 16 KB (dbuf)
  __shared__ float g5[8][320];   // gate tiles, stride-5 (conflict-free)
  __shared__ float s5[8][320];   // Wd partials, stride-5

  const int tid = threadIdx.x, bid = blockIdx.x;
  const int bg = bid & 3;          // batch group (16-block exchange group)
  const int cs = bid >> 2;         // col slice [0,16): h-cols cs*32..cs*32+32
  const int wv = tid >> 6, ln = tid & 63;
  const int lm = ln & 15, lg = ln >> 4;   // MFMA lane decomposition

  // ---------------- one-time: weights -> VGPRs (bf16 B-fragments) -----------
  const int gcol = (wv >> 1) * kH + cs * 32 + (wv & 1) * 16 + lm;
  short8v bU[16];                                   // U[512][gcol]
  #pragma unroll
  for (int kt = 0; kt < 16; ++kt) {
    short8v v;
    #pragma unroll
    for (int e = 0; e < 8; ++e)
      v[e] = (short)f2bf(U[(size_t)(kt * 32 + lg * 8 + e) * kG + gcol]);
    bU[kt] = v;
  }
  short8v bX[8];                                    // W[256][gcol]
  #pragma unroll
  for (int kt = 0; kt < 8; ++kt) {
    short8v v;
    #pragma unroll
    for (int e = 0; e < 8; ++e)
      v[e] = (short)f2bf(W[(size_t)(kt * 32 + lg * 8 + e) * kG + gcol]);
    bX[kt] = v;
  }
  const int kq = wv >> 1, ns = wv & 1;   // Wd: k-quarter kq, n-tile ns
  short8v bWd[4];
  #pragma unroll
  for (int kt = 0; kt < 4; ++kt) {
    short8v v;
    #pragma unroll
    for (int e = 0; e < 8; ++e)
      v[e] = (short)f2bf(Wd[(size_t)(kq * 128 + kt * 32 + lg * 8 + e) * kH
                            + cs * 32 + ns * 16 + lm]);
    bWd[kt] = v;
  }
  const float bias_r = bias[gcol];

  // ---------------- identities ----------------
  const int r = tid & 15, ch = tid >> 4, rs = r & 7;   // x staging
  const int bgl_r = bg * 16 + r;
  const int row2 = ln >> 2, q = ln & 3;                // hc staging (per wave)
  const int cm = tid >> 5, cj = tid & 31;              // cell: batch cm, col cj
  const int lidx = ((cm >> 2) << 4) | (cj & 15), jr = cm & 3, chf = cj >> 4;
  const size_t bglc = (size_t)bg * 16 + cm;
  const int colg = cs * 32 + cj;
  float c_keep = 0.0f;                                 // exact f32 cell carry
  float o_hold = 0.0f;                                 // deferred out value
  const size_t HID = (size_t)kB * kT * kH;

  // ---------------- prologue: stage x[0], prefetch x[1], tdel[0] ------------
  {
    const float* xs = inp + ((size_t)bgl_r * kT + 0) * kD + ch * 8;
    float4 a = *(const float4*)xs, b = *(const float4*)(xs + 4);
    uint4v xv;
    xv.x = (unsigned)f2bf(a.x) | ((unsigned)f2bf(a.y) << 16);
    xv.y = (unsigned)f2bf(a.z) | ((unsigned)f2bf(a.w) << 16);
    xv.z = (unsigned)f2bf(b.x) | ((unsigned)f2bf(b.y) << 16);
    xv.w = (unsigned)f2bf(b.z) | ((unsigned)f2bf(b.w) << 16);
    *(uint4v*)&x_lds[0][r][(ch ^ rs) * 8] = xv;
  }
  float4 xa, xb;
  {
    const float* xs = inp + ((size_t)bgl_r * kT + 1) * kD + ch * 8;
    xa = *(const float4*)xs; xb = *(const float4*)(xs + 4);
  }
  float tdv = tdel[bglc * kT + 0];
  __syncthreads();

  for (int t = 0; t < kT; ++t) {
    // ============ phase 1: x-stage -> xgemm(4) -> spec -> xgemm(4) -> valid =
    if (t + 1 < kT) {   // stage x[t+1] into the other buffer (regs from ph2(t-1))
      uint4v xv;
      xv.x = (unsigned)f2bf(xa.x) | ((unsigned)f2bf(xa.y) << 16);
      xv.y = (unsigned)f2bf(xa.z) | ((unsigned)f2bf(xa.w) << 16);
      xv.z = (unsigned)f2bf(xb.x) | ((unsigned)f2bf(xb.y) << 16);
      xv.w = (unsigned)f2bf(xb.z) | ((unsigned)f2bf(xb.w) << 16);
      *(uint4v*)&x_lds[(t + 1) & 1][r][(ch ^ rs) * 8] = xv;
    }
    const int xpar = t & 1;
    f32x4 xacc = {bias_r, bias_r, bias_r, bias_r};
    #pragma unroll
    for (int kt = 0; kt < 4; ++kt) {
      short8v av = *(const short8v*)&x_lds[xpar][lm][((kt * 4 + lg) ^ (lm & 7)) * 8];
      xacc = __builtin_amdgcn_mfma_f32_16x16x32_bf16(av, bX[kt], xacc, 0, 0, 0);
    }
    uint4v w0, w1, w2, w3;
    const unsigned* src = nullptr;
    if (t > 0) {   // spec issue mid-xgemm: late enough for visibility,
                   // early enough that the tail MFMAs hide part of the RTT
      __builtin_amdgcn_sched_barrier(0);
      src = hc + ((size_t)((t - 1) & 1) * kB + bg * 16 + row2) * kH
               + 64 * wv + 16 * q;
      asm volatile(
        "global_load_dwordx4 %0, %4, off sc1\n\t"
        "global_load_dwordx4 %1, %4, off offset:16 sc1\n\t"
        "global_load_dwordx4 %2, %4, off offset:32 sc1\n\t"
        "global_load_dwordx4 %3, %4, off offset:48 sc1"
        : "=&v"(w0), "=&v"(w1), "=&v"(w2), "=&v"(w3)
        : "v"(src) : "memory");
      __builtin_amdgcn_sched_barrier(0);
    }
    #pragma unroll
    for (int kt = 4; kt < 8; ++kt) {
      short8v av = *(const short8v*)&x_lds[xpar][lm][((kt * 4 + lg) ^ (lm & 7)) * 8];
      xacc = __builtin_amdgcn_mfma_f32_16x16x32_bf16(av, bX[kt], xacc, 0, 0, 0);
    }
    if (t > 0) {
      asm volatile("s_waitcnt vmcnt(0)" ::: "memory");
      __builtin_amdgcn_sched_barrier(0);
      const unsigned ep = (((unsigned)(t - 1) >> 1) & 1u) << 14;
      unsigned bad = (w0.x ^ ep) | (w0.y ^ ep) | (w0.z ^ ep) | (w0.w ^ ep)
                   | (w1.x ^ ep) | (w1.y ^ ep) | (w1.z ^ ep) | (w1.w ^ ep)
                   | (w2.x ^ ep) | (w2.y ^ ep) | (w2.z ^ ep) | (w2.w ^ ep)
                   | (w3.x ^ ep) | (w3.y ^ ep) | (w3.z ^ ep) | (w3.w ^ ep);
      bool ok = ((bad & 0x4000u) == 0u);
      int vt = 0;
      while (!__all(ok)) {
        if (++vt > (1 << 16)) break;   // safety valve: fail loud, not hung
        if (vt > 2) asm volatile("s_sleep 1" ::: "memory");
        if (!ok) {   // predicated: only stale lanes reload
          asm volatile(
            "global_load_dwordx4 %0, %4, off sc1\n\t"
            "global_load_dwordx4 %1, %4, off offset:16 sc1\n\t"
            "global_load_dwordx4 %2, %4, off offset:32 sc1\n\t"
            "global_load_dwordx4 %3, %4, off offset:48 sc1\n\t"
            "s_waitcnt vmcnt(0)"
            : "=&v"(w0), "=&v"(w1), "=&v"(w2), "=&v"(w3)
            : "v"(src) : "memory");
          __builtin_amdgcn_sched_barrier(0);
          bad = (w0.x ^ ep) | (w0.y ^ ep) | (w0.z ^ ep) | (w0.w ^ ep)
              | (w1.x ^ ep) | (w1.y ^ ep) | (w1.z ^ ep) | (w1.w ^ ep)
              | (w2.x ^ ep) | (w2.y ^ ep) | (w2.z ^ ep) | (w2.w ^ ep)
              | (w3.x ^ ep) | (w3.y ^ ep) | (w3.z ^ ep) | (w3.w ^ ep);
          ok = ((bad & 0x4000u) == 0u);
        }
      }
      // unpack: word = (h<<16) | c (bit14 = epoch tag, masked off)
      uint4v hA, hB, cA, cB;
      hA.x = (w0.x >> 16) | (w0.y & 0xFFFF0000u);
      hA.y = (w0.z >> 16) | (w0.w & 0xFFFF0000u);
      hA.z = (w1.x >> 16) | (w1.y & 0xFFFF0000u);
      hA.w = (w1.z >> 16) | (w1.w & 0xFFFF0000u);
      hB.x = (w2.x >> 16) | (w2.y & 0xFFFF0000u);
      hB.y = (w2.z >> 16) | (w2.w & 0xFFFF0000u);
      hB.z = (w3.x >> 16) | (w3.y & 0xFFFF0000u);
      hB.w = (w3.z >> 16) | (w3.w & 0xFFFF0000u);
      cA.x = (w0.x & 0xBFFFu) | ((w0.y & 0xBFFFu) << 16);
      cA.y = (w0.z & 0xBFFFu) | ((w0.w & 0xBFFFu) << 16);
      cA.z = (w1.x & 0xBFFFu) | ((w1.y & 0xBFFFu) << 16);
      cA.w = (w1.z & 0xBFFFu) | ((w1.w & 0xBFFFu) << 16);
      cB.x = (w2.x & 0xBFFFu) | ((w2.y & 0xBFFFu) << 16);
      cB.y = (w2.z & 0xBFFFu) | ((w2.w & 0xBFFFu) << 16);
      cB.z = (w3.x & 0xBFFFu) | ((w3.y & 0xBFFFu) << 16);
      cB.w = (w3.z & 0xBFFFu) | ((w3.w & 0xBFFFu) << 16);
      const int rsw = row2 & 7;
      const int ub = 8 * wv + 2 * q;
      *(uint4v*)&h_lds[row2][((ub)     ^ rsw) * 8] = hA;
      *(uint4v*)&h_lds[row2][((ub + 1) ^ rsw) * 8] = hB;
      *(uint4v*)&c_lds[row2][((ub)     ^ rsw) * 8] = cA;
      *(uint4v*)&c_lds[row2][((ub + 1) ^ rsw) * 8] = cB;
    }
    LGKM_BARRIER();                                    // barrier A

    // ============ phase 2: slow VMEM issues + GEMM ==========================
    if (t > 0)   // plain store: L2 ack, never holds a later vmcnt(0) long
      out[(bglc * kT + (t - 1)) * kH + colg] = o_hold;
    if (t + 2 < kT) {   // prefetch x[t+2] (HBM; completes during GEMM+cell)
      const float* xs = inp + ((size_t)bgl_r * kT + (t + 2)) * kD + ch * 8;
      xa = *(const float4*)xs; xb = *(const float4*)(xs + 4);
    }
    float tdn = (t + 1 < kT) ? tdel[bglc * kT + (t + 1)] : 0.0f;
    if (t > 0) {
      f32x4 a0 = xacc, a1 = {0.f, 0.f, 0.f, 0.f};
      #pragma unroll
      for (int kt = 0; kt < 8; ++kt) {
        short8v av = *(const short8v*)&h_lds[lm][((kt * 4 + lg) ^ (lm & 7)) * 8];
        a0 = __builtin_amdgcn_mfma_f32_16x16x32_bf16(av, bU[kt], a0, 0, 0, 0);
      }
      #pragma unroll
      for (int kt = 8; kt < 16; ++kt) {
        short8v av = *(const short8v*)&h_lds[lm][((kt * 4 + lg) ^ (lm & 7)) * 8];
        a1 = __builtin_amdgcn_mfma_f32_16x16x32_bf16(av, bU[kt], a1, 0, 0, 0);
      }
      f32x4 aw = {0.f, 0.f, 0.f, 0.f};
      #pragma unroll
      for (int kt = 0; kt < 4; ++kt) {
        short8v av = *(const short8v*)&c_lds[lm][((kq * 16 + kt * 4 + lg) ^ (lm & 7)) * 8];
        aw = __builtin_amdgcn_mfma_f32_16x16x32_bf16(av, bWd[kt], aw, 0, 0, 0);
      }
      #pragma unroll
      for (int j = 0; j < 4; ++j) {
        g5[wv][ln * 5 + j] = a0[j] + a1[j];
        s5[wv][ln * 5 + j] = aw[j];
      }
    } else {
      #pragma unroll
      for (int j = 0; j < 4; ++j) g5[wv][ln * 5 + j] = xacc[j];
    }
    LGKM_BARRIER();                                    // barrier B

    // ============ phase 3: cell -> tagged hc store (no flag, no barrier) ====
    {
      float g0 = g5[0 + chf][lidx * 5 + jr];
      float g1 = g5[2 + chf][lidx * 5 + jr];
      float g2 = g5[4 + chf][lidx * 5 + jr];
      float g3 = g5[6 + chf][lidx * 5 + jr];
      float sw = 0.f;
      if (t > 0) {
        #pragma unroll
        for (int q2 = 0; q2 < 4; ++q2) sw += s5[2 * q2 + chf][lidx * 5 + jr];
      }
      float csv  = ftanh(sw);
      float cadj = (c_keep - csv) + csv / __logf(2.71828182845904523536f + tdv);
      float gi = fsig(g0), gf = fsig(g1), gg = ftanh(g2), go = fsig(g3);
      float cnew = fmaf(gf, cadj, gi * gg);
      float tcn  = ftanh(cnew);            // = c_out
      float hout = ftanh(go * tcn);        // = tanh(o * tanh(c_new))
      c_keep = tcn;
      o_hold = hout;
      unsigned wout = ((unsigned)f2bf(hout) << 16) | (unsigned)f2bf(tcn)
                    | (((unsigned)(t >> 1) & 1u) << 14);
      unsigned* dst = hc + ((size_t)(t & 1) * kB + bglc) * kH + colg;
      asm volatile("global_store_dword %0, %1, off sc1"
                   :: "v"(dst), "v"(wout) : "memory");
    }
    tdv = tdn;
    // no barrier C: barrier A of the next step orders g5/s5 reuse; x_lds is
    // double-buffered; hc readers self-validate via the epoch tag.
  }

  // ---------------- epilogue: t = kT-1 outputs ------------------------------
  out[(bglc * kT + (kT - 1)) * kH + colg] = o_hold;
  out[HID + bglc * kH + colg] = o_hold;                      // h_t
  out[HID + (size_t)kB * kH + bglc * kH + colg] = c_keep;    // c_t
}

extern "C" void kernel_launch(void* const* d_in, const int* in_sizes, int n_in,
                              void* d_out, int out_size, void* d_ws, size_t ws_size,
                              hipStream_t stream)
{
  const float* inp  = (const float*)d_in[0];
  const float* td   = (const float*)d_in[1];
  const float* Wd   = (const float*)d_in[2];
  const float* W    = (const float*)d_in[3];
  const float* U    = (const float*)d_in[4];
  const float* bias = (const float*)d_in[5];
  float* out = (float*)d_out;

  // ws: hc[2][64][512] u32 (256 KB). Memset 0xFF each launch: tag bit14=1
  // everywhere -> t=1 (epoch 0) rejects any stale/poisoned data.
  unsigned* hc = (unsigned*)d_ws;
  (void)hipMemsetAsync(hc, 0xFF, (size_t)2 * kB * kH * sizeof(unsigned), stream);
  mtsltm_kernel<<<dim3(NBLK), dim3(NTHR), 0, stream>>>(inp, td, Wd, W, U, bias,
                                                       out, hc);
}